// Round 15
// baseline (682.263 us; speedup 1.0000x reference)
//
#include <hip/hip_runtime.h>
#include <hip/hip_bf16.h>

typedef __attribute__((ext_vector_type(8))) short  s16x8;
typedef __attribute__((ext_vector_type(4))) float  f32x4;

constexpr int EMB  = 16;
constexpr int LAT  = 8;
constexpr int EDIM = 32;
constexpr int HID  = 64;

constexpr int BSHIFT = 7;                 // 128 nodes per bucket
constexpr int BNODES = 1 << BSHIFT;
constexpr int PCHUNK = 8192;              // edges per partition block
constexpr int PERSIST = 1536;             // persistent blocks (6/CU x 256 CU)

__device__ __forceinline__ short f2b(float f) {
  __hip_bfloat16 h = __float2bfloat16(f);
  return __builtin_bit_cast(short, h);
}
__device__ __forceinline__ float asf(unsigned int u) { return __builtin_bit_cast(float, u); }
__device__ __forceinline__ unsigned int pk2(float lo, float hi) {
  return ((unsigned int)(unsigned short)f2b(hi) << 16) |
         (unsigned int)(unsigned short)f2b(lo);
}

// fixed-point scale 2^40 (deterministic i64 aggregation)
#define FIXSCALE 1.0995116277760e12f
#define FIXINV   9.094947017729282e-13

// ---------------------------------------------------------------------------
// Prep (all bf16):
//  W1f  fragment-major: [(ct*4+lh)*16+ll][8j] = W1[(lh*8+j)*64 + ct*16+ll]
//  W2p  GEMM2' fragments, k-map g(kt,lh,j)=(kt*2+(j>>2))*16+lh*4+(j&3)
//       + column perm pi: i = 2*ct2+((r>>1)&1), o = 2*(r>>2)+(r&1)
//  b2pp packed epilogue bias
//  dW1f fragment-major with K-pad zeros baked in (4096 entries; lh>=2 zero)
//  dW2p dec GEMM2' fragments
// ---------------------------------------------------------------------------
__global__ void prep_kernel(const float* __restrict__ W1, const float* __restrict__ W2,
                            const float* __restrict__ b2,
                            const float* __restrict__ dW1, const float* __restrict__ dW2,
                            short* __restrict__ W1f, short* __restrict__ W2p,
                            unsigned int* __restrict__ b2pp,
                            short* __restrict__ dW1f, short* __restrict__ dW2p) {
  int t = blockIdx.x * blockDim.x + threadIdx.x;
  if (t < 2048) {
    int j = t & 7, ll = (t >> 3) & 15, lh = (t >> 7) & 3, ct = t >> 9;
    W1f[t] = f2b(W1[(lh * 8 + j) * 64 + ct * 16 + ll]);
  }
  if (t < 8192) {
    int ct2 = t >> 10, kt = (t >> 9) & 1, lh = (t >> 7) & 3, r = (t >> 3) & 15, j = t & 7;
    int k = (kt * 2 + (j >> 2)) * 16 + lh * 4 + (j & 3);
    int i = 2 * ct2 + ((r >> 1) & 1);
    int o = 2 * (r >> 2) + (r & 1);
    W2p[t] = f2b(W2[k * 128 + i * 8 + o]);
  }
  if (t < 64) {
    int lh = t >> 4, slot = t & 15;
    int ct2 = slot >> 1, ih = slot & 1;
    int i = 2 * ct2 + ih;
    unsigned int lo = (unsigned short)f2b(b2[i * 8 + 2 * lh]);
    unsigned int hi = (unsigned short)f2b(b2[i * 8 + 2 * lh + 1]);
    b2pp[t] = (hi << 16) | lo;
  }
  if (t < 4096) {
    int j = t & 7, ll = (t >> 3) & 15, lh = (t >> 7) & 3, ct = t >> 9;  // ct<4
    dW1f[t] = (lh < 2) ? f2b(dW1[(lh * 8 + j) * 64 + ct * 16 + ll]) : (short)0;
  }
  if (t < 2048) {
    int ct2 = t >> 10, kt = (t >> 9) & 1, lh = (t >> 7) & 3, r = (t >> 3) & 15, j = t & 7;
    int k = (kt * 2 + (j >> 2)) * 16 + lh * 4 + (j & 3);
    dW2p[t] = f2b(dW2[k * 32 + ct2 * 16 + r]);
  }
}

// ---------------------------------------------------------------------------
// Bucket histogram + single-block exclusive scan + partition
// ---------------------------------------------------------------------------
__global__ __launch_bounds__(256) void bhist_kernel(const int* __restrict__ ei,
                                                    int* __restrict__ bins,
                                                    int E, int nbuck) {
  __shared__ int h[1024];
  for (int i = threadIdx.x; i < nbuck; i += 256) h[i] = 0;
  __syncthreads();
  for (int e = blockIdx.x * blockDim.x + threadIdx.x; e < E; e += gridDim.x * blockDim.x)
    atomicAdd(&h[ei[E + e] >> BSHIFT], 1);
  __syncthreads();
  for (int i = threadIdx.x; i < nbuck; i += 256)
    if (h[i]) atomicAdd(&bins[i], h[i]);
}

__global__ __launch_bounds__(1024) void bscan_kernel(const int* __restrict__ bins,
                                                     int* __restrict__ bases,
                                                     int* __restrict__ cursor, int nbuck) {
  __shared__ int sh[1024];
  int tid = threadIdx.x;
  int v = (tid < nbuck) ? bins[tid] : 0;
  sh[tid] = v;
  __syncthreads();
  for (int off = 1; off < 1024; off <<= 1) {
    int t = (tid >= off) ? sh[tid - off] : 0;
    __syncthreads();
    sh[tid] += t;
    __syncthreads();
  }
  int ex = sh[tid] - v;
  if (tid < nbuck) { bases[tid] = ex; cursor[tid] = ex; }
  if (tid == 0) bases[nbuck] = sh[1023];
}

__global__ __launch_bounds__(256) void part_kernel(const int* __restrict__ ei,
                                                   int* __restrict__ cursor,
                                                   unsigned int* __restrict__ recs,
                                                   int E, int nbuck) {
  __shared__ int h[1024];
  __shared__ int gcl[1024];
  __shared__ int lr[1024];
  const int tid  = threadIdx.x;
  const int base = blockIdx.x * PCHUNK;

  for (int i = tid; i < nbuck; i += 256) { h[i] = 0; lr[i] = 0; }
  __syncthreads();
  for (int i = tid; i < PCHUNK; i += 256) {
    int e = base + i;
    if (e < E) atomicAdd(&h[ei[E + e] >> BSHIFT], 1);
  }
  __syncthreads();
  for (int i = tid; i < nbuck; i += 256)
    gcl[i] = h[i] ? atomicAdd(&cursor[i], h[i]) : 0;
  __syncthreads();
  for (int i = tid; i < PCHUNK; i += 256) {
    int e = base + i;
    if (e >= E) continue;
    int tgt = ei[E + e];
    int b = tgt >> BSHIFT;
    int p = gcl[b] + atomicAdd(&lr[b], 1);
    recs[p] = ((unsigned int)e << BSHIFT) | (unsigned int)(tgt & (BNODES - 1));
  }
}

// ---------------------------------------------------------------------------
// Encoder: persistent grid-stride blocks, weights staged ONCE per block,
// fragment-major W1f (conflict-free), EDGE-ORDER coalesced bf16 store.
// (256,6): 24 waves/CU for latency hiding (VGPR demand ~56 << cap 85).
// ---------------------------------------------------------------------------
__global__ __launch_bounds__(256, 6) void enc_mfma_kernel(
    const int* __restrict__ ei, const float* __restrict__ attr,
    const float* __restrict__ emb,
    const short* __restrict__ W1f, const float* __restrict__ b1,
    const short* __restrict__ W2p, const unsigned int* __restrict__ b2pp,
    short* __restrict__ ms, int E, int ntiles) {
  __shared__ short lds_w1[2048];          // fragment-major
  __shared__ short lds_w2[8192];          // GEMM2' fragments
  __shared__ float lds_b1[64];
  __shared__ unsigned int lds_b2[64];

  const int tid = threadIdx.x;
  const int w = tid >> 6, l = tid & 63;
  const int lh = l >> 4, ll = l & 15;

  // cooperative weight staging (once per persistent block)
  {
    reinterpret_cast<int4*>(lds_w1)[tid] = reinterpret_cast<const int4*>(W1f)[tid];
#pragma unroll
    for (int i = 0; i < 4; i++)
      reinterpret_cast<int4*>(lds_w2)[i * 256 + tid] =
          reinterpret_cast<const int4*>(W2p)[i * 256 + tid];
    if (tid < 64) lds_b1[tid] = b1[tid];
    if (tid < 64) lds_b2[tid] = b2pp[tid];
  }
  __syncthreads();

  const f32x4 z = {0.f, 0.f, 0.f, 0.f};

  for (int tile = blockIdx.x; tile < ntiles; tile += gridDim.x) {
    const int ebase = tile * 256 + w * 64;

    // gather src embedding for this lane's edge, pack to bf16 pairs
    unsigned int xqp[8];
    {
      int ec = min(ebase + l, E - 1);
      int src = ei[ec];
      const float4* er = reinterpret_cast<const float4*>(emb) + (size_t)src * 4;
      float4 v0 = er[0], v1 = er[1], v2 = er[2], v3 = er[3];
      xqp[0] = pk2(v0.x, v0.y); xqp[1] = pk2(v0.z, v0.w);
      xqp[2] = pk2(v1.x, v1.y); xqp[3] = pk2(v1.z, v1.w);
      xqp[4] = pk2(v2.x, v2.y); xqp[5] = pk2(v2.z, v2.w);
      xqp[6] = pk2(v3.x, v3.y); xqp[7] = pk2(v3.z, v3.w);
    }

    // prefetch attr rows for all 4 tiles, convert to bf16 fragments
    s16x8 afs[4];
#pragma unroll
    for (int mt = 0; mt < 4; mt++) {
      int rowA = min(ebase + mt * 16 + ll, E - 1);
      const float4* ap = reinterpret_cast<const float4*>(attr + (size_t)rowA * EDIM + lh * 8);
      float4 a0 = ap[0], a1 = ap[1];
      afs[mt][0]=f2b(a0.x); afs[mt][1]=f2b(a0.y); afs[mt][2]=f2b(a0.z); afs[mt][3]=f2b(a0.w);
      afs[mt][4]=f2b(a1.x); afs[mt][5]=f2b(a1.y); afs[mt][6]=f2b(a1.z); afs[mt][7]=f2b(a1.w);
    }

#pragma unroll
    for (int mt = 0; mt < 4; mt++) {
      // GEMM1' -> H^T fragments (fragment-major: conflict-free)
      f32x4 c1t[4];
#pragma unroll
      for (int ct = 0; ct < 4; ct++) {
        s16x8 b1f = *reinterpret_cast<const s16x8*>(lds_w1 + ((ct * 4 + lh) * 16 + ll) * 8);
        c1t[ct] = __builtin_amdgcn_mfma_f32_16x16x32_bf16(b1f, afs[mt], z, 0, 0, 0);
      }

      short hb[4][4];
#pragma unroll
      for (int ct = 0; ct < 4; ct++) {
        float4 bv = *reinterpret_cast<const float4*>(lds_b1 + ct * 16 + lh * 4);  // broadcast
        hb[ct][0] = f2b(fmaxf(c1t[ct][0] + bv.x, 0.f));
        hb[ct][1] = f2b(fmaxf(c1t[ct][1] + bv.y, 0.f));
        hb[ct][2] = f2b(fmaxf(c1t[ct][2] + bv.z, 0.f));
        hb[ct][3] = f2b(fmaxf(c1t[ct][3] + bv.w, 0.f));
      }
      s16x8 a2f0, a2f1;
#pragma unroll
      for (int j = 0; j < 8; j++) a2f0[j] = hb[(j >> 2)][j & 3];
#pragma unroll
      for (int j = 0; j < 8; j++) a2f1[j] = hb[2 + (j >> 2)][j & 3];

      // fetch xe pairs of edge mt*16+ll (from the owning lane)
      const int srcl = mt * 16 + ll;
      unsigned int xs[8];
#pragma unroll
      for (int c = 0; c < 8; c++)
        xs[c] = (unsigned int)__shfl((int)xqp[c], srcl, 64);

      // GEMM2' + lane-local epilogue with bias
      float q0 = 0.f, q1 = 0.f;
#pragma unroll
      for (int ct2 = 0; ct2 < 8; ct2++) {
        s16x8 f0 = *reinterpret_cast<const s16x8*>(lds_w2 + ((ct2 * 2 + 0) * 4 + lh) * 128 + ll * 8);
        s16x8 f1 = *reinterpret_cast<const s16x8*>(lds_w2 + ((ct2 * 2 + 1) * 4 + lh) * 128 + ll * 8);
        f32x4 c2 = __builtin_amdgcn_mfma_f32_16x16x32_bf16(f0, a2f0, z, 0, 0, 0);
        c2 = __builtin_amdgcn_mfma_f32_16x16x32_bf16(f1, a2f1, c2, 0, 0, 0);
        uint2 pp = *reinterpret_cast<const uint2*>(lds_b2 + lh * 16 + 2 * ct2);  // broadcast
        float b00 = asf(pp.x << 16), b01 = asf(pp.x & 0xffff0000u);
        float b10 = asf(pp.y << 16), b11 = asf(pp.y & 0xffff0000u);
        float xv0 = asf(xs[ct2] << 16);          // xe[2*ct2]
        float xv1 = asf(xs[ct2] & 0xffff0000u);  // xe[2*ct2+1]
        q0 = fmaf(xv0, c2[0] + b00, q0);
        q1 = fmaf(xv0, c2[1] + b01, q1);
        q0 = fmaf(xv1, c2[2] + b10, q0);
        q1 = fmaf(xv1, c2[3] + b11, q1);
      }
      // coalesced bf16 store in EDGE order
      int e = ebase + mt * 16 + ll;
      if (e < E)
        *reinterpret_cast<unsigned int*>(ms + (size_t)e * LAT + 2 * lh) = pk2(q0, q1);
    }
  }
}

// ---------------------------------------------------------------------------
// Aggregate: one block per bucket. Contiguous record read, random ms gather
// (L3-resident), deterministic i64 fixed-point LDS accumulation (padded rows),
// then mean + conv_b + emb@rootW -> latent.
// ---------------------------------------------------------------------------
__global__ __launch_bounds__(256) void agg_kernel(
    const float* __restrict__ emb, const short* __restrict__ ms,
    const unsigned int* __restrict__ recs, const int* __restrict__ bases,
    const float* __restrict__ rootW, const float* __restrict__ convb,
    float* __restrict__ latent, int N) {
  __shared__ long long acc[BNODES][LAT + 1];   // 72B rows: bank de-alias
  __shared__ int cnt[BNODES];
  __shared__ float rw[EMB * LAT];
  __shared__ float cb[LAT];

  const int tid = threadIdx.x;
  const int b = blockIdx.x;

  long long* af = &acc[0][0];
  for (int i = tid; i < BNODES * (LAT + 1); i += 256) af[i] = 0;
  if (tid < BNODES) cnt[tid] = 0;
  if (tid < EMB * LAT) rw[tid] = rootW[tid];
  if (tid < LAT) cb[tid] = convb[tid];
  __syncthreads();

  const int s = bases[b], epos = bases[b + 1];
  const uint4* mp = reinterpret_cast<const uint4*>(ms);
  for (int i = s + tid; i < epos; i += 256) {
    unsigned int r = recs[i];
    int eid = (int)(r >> BSHIFT);
    int tl  = (int)(r & (BNODES - 1));
    uint4 m = mp[(size_t)eid];
    float f0 = asf(m.x << 16), f1 = asf(m.x & 0xffff0000u);
    float f2 = asf(m.y << 16), f3 = asf(m.y & 0xffff0000u);
    float f4 = asf(m.z << 16), f5 = asf(m.z & 0xffff0000u);
    float f6 = asf(m.w << 16), f7 = asf(m.w & 0xffff0000u);
    atomicAdd((unsigned long long*)&acc[tl][0], (unsigned long long)(long long)(f0 * FIXSCALE));
    atomicAdd((unsigned long long*)&acc[tl][1], (unsigned long long)(long long)(f1 * FIXSCALE));
    atomicAdd((unsigned long long*)&acc[tl][2], (unsigned long long)(long long)(f2 * FIXSCALE));
    atomicAdd((unsigned long long*)&acc[tl][3], (unsigned long long)(long long)(f3 * FIXSCALE));
    atomicAdd((unsigned long long*)&acc[tl][4], (unsigned long long)(long long)(f4 * FIXSCALE));
    atomicAdd((unsigned long long*)&acc[tl][5], (unsigned long long)(long long)(f5 * FIXSCALE));
    atomicAdd((unsigned long long*)&acc[tl][6], (unsigned long long)(long long)(f6 * FIXSCALE));
    atomicAdd((unsigned long long*)&acc[tl][7], (unsigned long long)(long long)(f7 * FIXSCALE));
    atomicAdd(&cnt[tl], 1);
  }
  __syncthreads();

  int n = b * BNODES + tid;
  if (tid < BNODES && n < N) {
    float inv = 1.f / fmaxf((float)cnt[tid], 1.f);
    float r[LAT];
#pragma unroll
    for (int o = 0; o < LAT; o++)
      r[o] = fmaf((float)((double)acc[tid][o] * FIXINV), inv, cb[o]);

    float x[EMB];
    const float4* np4 = reinterpret_cast<const float4*>(emb) + (size_t)n * (EMB / 4);
#pragma unroll
    for (int i = 0; i < EMB / 4; i++) {
      float4 v = np4[i];
      x[4 * i + 0] = v.x; x[4 * i + 1] = v.y; x[4 * i + 2] = v.z; x[4 * i + 3] = v.w;
    }
#pragma unroll
    for (int i = 0; i < EMB; i++)
#pragma unroll
      for (int o = 0; o < LAT; o++) r[o] = fmaf(x[i], rw[i * LAT + o], r[o]);

    float4* lp = reinterpret_cast<float4*>(latent) + (size_t)n * 2;
    lp[0] = make_float4(r[0], r[1], r[2], r[3]);
    lp[1] = make_float4(r[4], r[5], r[6], r[7]);
  }
}

// ---------------------------------------------------------------------------
// Decoder: persistent grid-stride blocks, weights staged once; fragment-major
// dW1f (K-pad baked), conflict-free LDS reads; (256,6) for latency hiding.
// ---------------------------------------------------------------------------
__global__ __launch_bounds__(256, 6) void dec_mfma_kernel(
    const int* __restrict__ ei, const float* __restrict__ lat,
    const short* __restrict__ dW1f, const float* __restrict__ db1,
    const short* __restrict__ dW2p, const float* __restrict__ db2,
    float* __restrict__ out, int E, int ntiles) {
  __shared__ short lds_w1[4096];   // fragment-major, lh>=2 zero
  __shared__ short lds_w2[2048];   // dec GEMM2' fragments
  __shared__ float lds_b1[64];
  __shared__ float lds_b2[32];

  const int tid = threadIdx.x;
  const int w = tid >> 6, l = tid & 63;
  const int lh = l >> 4, ll = l & 15;

  {
#pragma unroll
    for (int i = 0; i < 2; i++)
      reinterpret_cast<int4*>(lds_w1)[i * 256 + tid] =
          reinterpret_cast<const int4*>(dW1f)[i * 256 + tid];
    reinterpret_cast<int4*>(lds_w2)[tid] = reinterpret_cast<const int4*>(dW2p)[tid];
    if (tid < 64) lds_b1[tid] = db1[tid];
    if (tid < 32) lds_b2[tid] = db2[tid];
  }
  __syncthreads();

  const f32x4 z = {0.f, 0.f, 0.f, 0.f};

  for (int tile = blockIdx.x; tile < ntiles; tile += gridDim.x) {
    const int ebase = tile * 256 + w * 64;

#pragma unroll
    for (int mt = 0; mt < 4; mt++) {
      // latent halves: lh=0 -> src, lh=1 -> tgt, lh>=2 zero pad (k 16..31)
      s16x8 af = (s16x8){0, 0, 0, 0, 0, 0, 0, 0};
      if (lh < 2) {
        int rowA = min(ebase + mt * 16 + ll, E - 1);
        int node = ei[(lh == 0 ? 0 : E) + rowA];
        const float4* lp = reinterpret_cast<const float4*>(lat + (size_t)node * LAT);
        float4 p0 = lp[0], p1 = lp[1];
        af[0]=f2b(p0.x); af[1]=f2b(p0.y); af[2]=f2b(p0.z); af[3]=f2b(p0.w);
        af[4]=f2b(p1.x); af[5]=f2b(p1.y); af[6]=f2b(p1.z); af[7]=f2b(p1.w);
      }

      f32x4 c1t[4];
#pragma unroll
      for (int ct = 0; ct < 4; ct++) {
        s16x8 b1f = *reinterpret_cast<const s16x8*>(lds_w1 + ((ct * 4 + lh) * 16 + ll) * 8);
        c1t[ct] = __builtin_amdgcn_mfma_f32_16x16x32_bf16(b1f, af, z, 0, 0, 0);
      }

      short hb[4][4];
#pragma unroll
      for (int ct = 0; ct < 4; ct++) {
        float4 bv = *reinterpret_cast<const float4*>(lds_b1 + ct * 16 + lh * 4);  // broadcast
        hb[ct][0] = f2b(fmaxf(c1t[ct][0] + bv.x, 0.f));
        hb[ct][1] = f2b(fmaxf(c1t[ct][1] + bv.y, 0.f));
        hb[ct][2] = f2b(fmaxf(c1t[ct][2] + bv.z, 0.f));
        hb[ct][3] = f2b(fmaxf(c1t[ct][3] + bv.w, 0.f));
      }
      s16x8 a2f0, a2f1;
#pragma unroll
      for (int j = 0; j < 8; j++) a2f0[j] = hb[(j >> 2)][j & 3];
#pragma unroll
      for (int j = 0; j < 8; j++) a2f1[j] = hb[2 + (j >> 2)][j & 3];

      int e = ebase + mt * 16 + ll;
#pragma unroll
      for (int ct2 = 0; ct2 < 2; ct2++) {
        s16x8 f0 = *reinterpret_cast<const s16x8*>(lds_w2 + ((ct2 * 2 + 0) * 4 + lh) * 128 + ll * 8);
        s16x8 f1 = *reinterpret_cast<const s16x8*>(lds_w2 + ((ct2 * 2 + 1) * 4 + lh) * 128 + ll * 8);
        f32x4 c2 = __builtin_amdgcn_mfma_f32_16x16x32_bf16(f0, a2f0, z, 0, 0, 0);
        c2 = __builtin_amdgcn_mfma_f32_16x16x32_bf16(f1, a2f1, c2, 0, 0, 0);
        float4 bv = *reinterpret_cast<const float4*>(lds_b2 + ct2 * 16 + lh * 4);  // broadcast
        if (e < E)
          *reinterpret_cast<float4*>(out + (size_t)e * EDIM + ct2 * 16 + lh * 4) =
              make_float4(c2[0] + bv.x, c2[1] + bv.y, c2[2] + bv.z, c2[3] + bv.w);
      }
    }
  }
}

// ---------------------------------------------------------------------------
extern "C" void kernel_launch(void* const* d_in, const int* in_sizes, int n_in,
                              void* d_out, int out_size, void* d_ws, size_t ws_size,
                              hipStream_t stream) {
  const int*   ei    = (const int*)  d_in[0];
  const float* attr  = (const float*)d_in[1];
  const float* emb   = (const float*)d_in[2];
  const float* ewW1  = (const float*)d_in[3];
  const float* ewb1  = (const float*)d_in[4];
  const float* ewW2  = (const float*)d_in[5];
  const float* ewb2  = (const float*)d_in[6];
  const float* rootW = (const float*)d_in[7];
  const float* convb = (const float*)d_in[8];
  const float* dW1   = (const float*)d_in[9];
  const float* db1   = (const float*)d_in[10];
  const float* dW2   = (const float*)d_in[11];
  const float* db2   = (const float*)d_in[12];
  float* out = (float*)d_out;

  const int E      = in_sizes[0] / 2;
  const int N      = in_sizes[2] / EMB;
  const int nbuck  = (N + BNODES - 1) >> BSHIFT;
  const int ntiles = (E + 255) / 256;

  // workspace layout (weights first: 16B-aligned fragment loads)
  short* W1f  = (short*)d_ws;                   // 2048 shorts
  short* W2p  = W1f + 2048;                     // 8192
  short* dW1f = W2p + 8192;                     // 4096 (K-pad baked)
  short* dW2p = dW1f + 4096;                    // 2048
  unsigned int* b2pp = (unsigned int*)(dW2p + 2048);  // 64 u32
  short* ms   = (short*)(b2pp + 64);            // E*8 bf16 (16B/message)
  float* lat  = (float*)(ms + (size_t)E * LAT); // N*8
  unsigned int* recs = (unsigned int*)(lat + (size_t)N * LAT);  // E
  int* bins   = (int*)(recs + E);               // nbuck
  int* bases  = bins + nbuck;                   // nbuck+1
  int* cursor = bases + nbuck + 1;              // nbuck

  const int blocks_p = (E + PCHUNK - 1) / PCHUNK;
  const int grid_ed  = min(PERSIST, ntiles);

  hipMemsetAsync(bins, 0, (size_t)nbuck * sizeof(int), stream);
  prep_kernel<<<32, 256, 0, stream>>>(ewW1, ewW2, ewb2, dW1, dW2,
                                      W1f, W2p, b2pp, dW1f, dW2p);
  bhist_kernel<<<256, 256, 0, stream>>>(ei, bins, E, nbuck);
  bscan_kernel<<<1, 1024, 0, stream>>>(bins, bases, cursor, nbuck);
  part_kernel<<<blocks_p, 256, 0, stream>>>(ei, cursor, recs, E, nbuck);
  enc_mfma_kernel<<<grid_ed, 256, 0, stream>>>(ei, attr, emb, W1f, ewb1, W2p, b2pp,
                                               ms, E, ntiles);
  agg_kernel<<<nbuck, 256, 0, stream>>>(emb, ms, recs, bases, rootW, convb, lat, N);
  dec_mfma_kernel<<<grid_ed, 256, 0, stream>>>(ei, lat, dW1f, db1, dW2p, db2,
                                               out, E, ntiles);
}

// Round 16
// 216.273 us; speedup vs baseline: 3.1546x; 3.1546x over previous
//
#include <hip/hip_runtime.h>
#include <hip/hip_bf16.h>

typedef __attribute__((ext_vector_type(8))) short  s16x8;
typedef __attribute__((ext_vector_type(4))) float  f32x4;

constexpr int EMB  = 16;
constexpr int LAT  = 8;
constexpr int EDIM = 32;
constexpr int HID  = 64;

constexpr int BSHIFT = 7;                 // 128 nodes per bucket
constexpr int BNODES = 1 << BSHIFT;
constexpr int PCHUNK = 8192;              // edges per partition block

__device__ __forceinline__ short f2b(float f) {
  __hip_bfloat16 h = __float2bfloat16(f);
  return __builtin_bit_cast(short, h);
}
__device__ __forceinline__ float asf(unsigned int u) { return __builtin_bit_cast(float, u); }
__device__ __forceinline__ unsigned int pk2(float lo, float hi) {
  return ((unsigned int)(unsigned short)f2b(hi) << 16) |
         (unsigned int)(unsigned short)f2b(lo);
}

// fixed-point scale 2^40 (deterministic i64 aggregation)
#define FIXSCALE 1.0995116277760e12f
#define FIXINV   9.094947017729282e-13

// ---------------------------------------------------------------------------
// Prep (all bf16):
//  W1f  fragment-major: [(ct*4+lh)*16+ll][8j] = W1[(lh*8+j)*64 + ct*16+ll]
//  W2p  GEMM2' fragments, k-map g(kt,lh,j)=(kt*2+(j>>2))*16+lh*4+(j&3)
//       + column perm pi: i = 2*ct2+((r>>1)&1), o = 2*(r>>2)+(r&1)
//  b2pp packed epilogue bias
//  dW1f fragment-major with K-pad zeros baked in (4096 entries; lh>=2 zero)
//  dW2p dec GEMM2' fragments
// ---------------------------------------------------------------------------
__global__ void prep_kernel(const float* __restrict__ W1, const float* __restrict__ W2,
                            const float* __restrict__ b2,
                            const float* __restrict__ dW1, const float* __restrict__ dW2,
                            short* __restrict__ W1f, short* __restrict__ W2p,
                            unsigned int* __restrict__ b2pp,
                            short* __restrict__ dW1f, short* __restrict__ dW2p) {
  int t = blockIdx.x * blockDim.x + threadIdx.x;
  if (t < 2048) {
    int j = t & 7, ll = (t >> 3) & 15, lh = (t >> 7) & 3, ct = t >> 9;
    W1f[t] = f2b(W1[(lh * 8 + j) * 64 + ct * 16 + ll]);
  }
  if (t < 8192) {
    int ct2 = t >> 10, kt = (t >> 9) & 1, lh = (t >> 7) & 3, r = (t >> 3) & 15, j = t & 7;
    int k = (kt * 2 + (j >> 2)) * 16 + lh * 4 + (j & 3);
    int i = 2 * ct2 + ((r >> 1) & 1);
    int o = 2 * (r >> 2) + (r & 1);
    W2p[t] = f2b(W2[k * 128 + i * 8 + o]);
  }
  if (t < 64) {
    int lh = t >> 4, slot = t & 15;
    int ct2 = slot >> 1, ih = slot & 1;
    int i = 2 * ct2 + ih;
    unsigned int lo = (unsigned short)f2b(b2[i * 8 + 2 * lh]);
    unsigned int hi = (unsigned short)f2b(b2[i * 8 + 2 * lh + 1]);
    b2pp[t] = (hi << 16) | lo;
  }
  if (t < 4096) {
    int j = t & 7, ll = (t >> 3) & 15, lh = (t >> 7) & 3, ct = t >> 9;  // ct<4
    dW1f[t] = (lh < 2) ? f2b(dW1[(lh * 8 + j) * 64 + ct * 16 + ll]) : (short)0;
  }
  if (t < 2048) {
    int ct2 = t >> 10, kt = (t >> 9) & 1, lh = (t >> 7) & 3, r = (t >> 3) & 15, j = t & 7;
    int k = (kt * 2 + (j >> 2)) * 16 + lh * 4 + (j & 3);
    dW2p[t] = f2b(dW2[k * 32 + ct2 * 16 + r]);
  }
}

// ---------------------------------------------------------------------------
// Bucket histogram + single-block exclusive scan + partition
// ---------------------------------------------------------------------------
__global__ __launch_bounds__(256) void bhist_kernel(const int* __restrict__ ei,
                                                    int* __restrict__ bins,
                                                    int E, int nbuck) {
  __shared__ int h[1024];
  for (int i = threadIdx.x; i < nbuck; i += 256) h[i] = 0;
  __syncthreads();
  for (int e = blockIdx.x * blockDim.x + threadIdx.x; e < E; e += gridDim.x * blockDim.x)
    atomicAdd(&h[ei[E + e] >> BSHIFT], 1);
  __syncthreads();
  for (int i = threadIdx.x; i < nbuck; i += 256)
    if (h[i]) atomicAdd(&bins[i], h[i]);
}

__global__ __launch_bounds__(1024) void bscan_kernel(const int* __restrict__ bins,
                                                     int* __restrict__ bases,
                                                     int* __restrict__ cursor, int nbuck) {
  __shared__ int sh[1024];
  int tid = threadIdx.x;
  int v = (tid < nbuck) ? bins[tid] : 0;
  sh[tid] = v;
  __syncthreads();
  for (int off = 1; off < 1024; off <<= 1) {
    int t = (tid >= off) ? sh[tid - off] : 0;
    __syncthreads();
    sh[tid] += t;
    __syncthreads();
  }
  int ex = sh[tid] - v;
  if (tid < nbuck) { bases[tid] = ex; cursor[tid] = ex; }
  if (tid == 0) bases[nbuck] = sh[1023];
}

__global__ __launch_bounds__(256) void part_kernel(const int* __restrict__ ei,
                                                   int* __restrict__ cursor,
                                                   unsigned int* __restrict__ recs,
                                                   int E, int nbuck) {
  __shared__ int h[1024];
  __shared__ int gcl[1024];
  __shared__ int lr[1024];
  const int tid  = threadIdx.x;
  const int base = blockIdx.x * PCHUNK;

  for (int i = tid; i < nbuck; i += 256) { h[i] = 0; lr[i] = 0; }
  __syncthreads();
  for (int i = tid; i < PCHUNK; i += 256) {
    int e = base + i;
    if (e < E) atomicAdd(&h[ei[E + e] >> BSHIFT], 1);
  }
  __syncthreads();
  for (int i = tid; i < nbuck; i += 256)
    gcl[i] = h[i] ? atomicAdd(&cursor[i], h[i]) : 0;
  __syncthreads();
  for (int i = tid; i < PCHUNK; i += 256) {
    int e = base + i;
    if (e >= E) continue;
    int tgt = ei[E + e];
    int b = tgt >> BSHIFT;
    int p = gcl[b] + atomicAdd(&lr[b], 1);
    recs[p] = ((unsigned int)e << BSHIFT) | (unsigned int)(tgt & (BNODES - 1));
  }
}

// ---------------------------------------------------------------------------
// Encoder: weights LDS-staged (fragment-major W1f: conflict-free), attr
// prefetched, EDGE-ORDER coalesced bf16 message store (no atomics).
// (256,4): spill-free precedent from round 8 (heavier body, VGPR 60).
// ---------------------------------------------------------------------------
__global__ __launch_bounds__(256, 4) void enc_mfma_kernel(
    const int* __restrict__ ei, const float* __restrict__ attr,
    const float* __restrict__ emb,
    const short* __restrict__ W1f, const float* __restrict__ b1,
    const short* __restrict__ W2p, const unsigned int* __restrict__ b2pp,
    short* __restrict__ ms, int E) {
  __shared__ short lds_w1[2048];          // fragment-major
  __shared__ short lds_w2[8192];          // GEMM2' fragments
  __shared__ float lds_b1[64];
  __shared__ unsigned int lds_b2[64];

  const int tid = threadIdx.x;
  const int w = tid >> 6, l = tid & 63;
  const int lh = l >> 4, ll = l & 15;
  const int ebase = blockIdx.x * 256 + w * 64;

  // cooperative weight staging (coalesced 16B per thread)
  {
    reinterpret_cast<int4*>(lds_w1)[tid] = reinterpret_cast<const int4*>(W1f)[tid];
#pragma unroll
    for (int i = 0; i < 4; i++)
      reinterpret_cast<int4*>(lds_w2)[i * 256 + tid] =
          reinterpret_cast<const int4*>(W2p)[i * 256 + tid];
    if (tid < 64) lds_b1[tid] = b1[tid];
    if (tid < 64) lds_b2[tid] = b2pp[tid];
  }

  // phase 0: gather src embedding, pack to bf16 pairs
  unsigned int xqp[8];
  {
    int ec = min(ebase + l, E - 1);
    int src = ei[ec];
    const float4* er = reinterpret_cast<const float4*>(emb) + (size_t)src * 4;
    float4 v0 = er[0], v1 = er[1], v2 = er[2], v3 = er[3];
    xqp[0] = pk2(v0.x, v0.y); xqp[1] = pk2(v0.z, v0.w);
    xqp[2] = pk2(v1.x, v1.y); xqp[3] = pk2(v1.z, v1.w);
    xqp[4] = pk2(v2.x, v2.y); xqp[5] = pk2(v2.z, v2.w);
    xqp[6] = pk2(v3.x, v3.y); xqp[7] = pk2(v3.z, v3.w);
  }

  // prefetch attr rows for all 4 tiles, convert to bf16 fragments (16 regs)
  s16x8 afs[4];
#pragma unroll
  for (int mt = 0; mt < 4; mt++) {
    int rowA = min(ebase + mt * 16 + ll, E - 1);
    const float4* ap = reinterpret_cast<const float4*>(attr + (size_t)rowA * EDIM + lh * 8);
    float4 a0 = ap[0], a1 = ap[1];
    afs[mt][0]=f2b(a0.x); afs[mt][1]=f2b(a0.y); afs[mt][2]=f2b(a0.z); afs[mt][3]=f2b(a0.w);
    afs[mt][4]=f2b(a1.x); afs[mt][5]=f2b(a1.y); afs[mt][6]=f2b(a1.z); afs[mt][7]=f2b(a1.w);
  }

  __syncthreads();

  const f32x4 z = {0.f, 0.f, 0.f, 0.f};

#pragma unroll
  for (int mt = 0; mt < 4; mt++) {
    // GEMM1' -> H^T fragments (fragment-major: conflict-free)
    f32x4 c1t[4];
#pragma unroll
    for (int ct = 0; ct < 4; ct++) {
      s16x8 b1f = *reinterpret_cast<const s16x8*>(lds_w1 + ((ct * 4 + lh) * 16 + ll) * 8);
      c1t[ct] = __builtin_amdgcn_mfma_f32_16x16x32_bf16(b1f, afs[mt], z, 0, 0, 0);
    }

    short hb[4][4];
#pragma unroll
    for (int ct = 0; ct < 4; ct++) {
      float4 bv = *reinterpret_cast<const float4*>(lds_b1 + ct * 16 + lh * 4);  // broadcast
      hb[ct][0] = f2b(fmaxf(c1t[ct][0] + bv.x, 0.f));
      hb[ct][1] = f2b(fmaxf(c1t[ct][1] + bv.y, 0.f));
      hb[ct][2] = f2b(fmaxf(c1t[ct][2] + bv.z, 0.f));
      hb[ct][3] = f2b(fmaxf(c1t[ct][3] + bv.w, 0.f));
    }
    s16x8 a2f0, a2f1;
#pragma unroll
    for (int j = 0; j < 8; j++) a2f0[j] = hb[(j >> 2)][j & 3];
#pragma unroll
    for (int j = 0; j < 8; j++) a2f1[j] = hb[2 + (j >> 2)][j & 3];

    // fetch xe pairs of edge mt*16+ll (from the owning lane)
    const int srcl = mt * 16 + ll;
    unsigned int xs[8];
#pragma unroll
    for (int c = 0; c < 8; c++)
      xs[c] = (unsigned int)__shfl((int)xqp[c], srcl, 64);

    // GEMM2' + lane-local epilogue with bias (weights + bias from LDS)
    float q0 = 0.f, q1 = 0.f;
#pragma unroll
    for (int ct2 = 0; ct2 < 8; ct2++) {
      s16x8 f0 = *reinterpret_cast<const s16x8*>(lds_w2 + ((ct2 * 2 + 0) * 4 + lh) * 128 + ll * 8);
      s16x8 f1 = *reinterpret_cast<const s16x8*>(lds_w2 + ((ct2 * 2 + 1) * 4 + lh) * 128 + ll * 8);
      f32x4 c2 = __builtin_amdgcn_mfma_f32_16x16x32_bf16(f0, a2f0, z, 0, 0, 0);
      c2 = __builtin_amdgcn_mfma_f32_16x16x32_bf16(f1, a2f1, c2, 0, 0, 0);
      uint2 pp = *reinterpret_cast<const uint2*>(lds_b2 + lh * 16 + 2 * ct2);  // broadcast
      float b00 = asf(pp.x << 16), b01 = asf(pp.x & 0xffff0000u);
      float b10 = asf(pp.y << 16), b11 = asf(pp.y & 0xffff0000u);
      float xv0 = asf(xs[ct2] << 16);          // xe[2*ct2]
      float xv1 = asf(xs[ct2] & 0xffff0000u);  // xe[2*ct2+1]
      q0 = fmaf(xv0, c2[0] + b00, q0);
      q1 = fmaf(xv0, c2[1] + b01, q1);
      q0 = fmaf(xv1, c2[2] + b10, q0);
      q1 = fmaf(xv1, c2[3] + b11, q1);
    }
    // coalesced bf16 store in EDGE order
    int e = ebase + mt * 16 + ll;
    if (e < E)
      *reinterpret_cast<unsigned int*>(ms + (size_t)e * LAT + 2 * lh) = pk2(q0, q1);
  }
}

// ---------------------------------------------------------------------------
// Aggregate: one block per bucket. Contiguous record read, random ms gather
// (L3-resident), deterministic i64 fixed-point LDS accumulation (padded rows),
// then mean + conv_b + emb@rootW -> latent.
// ---------------------------------------------------------------------------
__global__ __launch_bounds__(256) void agg_kernel(
    const float* __restrict__ emb, const short* __restrict__ ms,
    const unsigned int* __restrict__ recs, const int* __restrict__ bases,
    const float* __restrict__ rootW, const float* __restrict__ convb,
    float* __restrict__ latent, int N) {
  __shared__ long long acc[BNODES][LAT + 1];   // 72B rows: bank de-alias
  __shared__ int cnt[BNODES];
  __shared__ float rw[EMB * LAT];
  __shared__ float cb[LAT];

  const int tid = threadIdx.x;
  const int b = blockIdx.x;

  long long* af = &acc[0][0];
  for (int i = tid; i < BNODES * (LAT + 1); i += 256) af[i] = 0;
  if (tid < BNODES) cnt[tid] = 0;
  if (tid < EMB * LAT) rw[tid] = rootW[tid];
  if (tid < LAT) cb[tid] = convb[tid];
  __syncthreads();

  const int s = bases[b], epos = bases[b + 1];
  const uint4* mp = reinterpret_cast<const uint4*>(ms);
  for (int i = s + tid; i < epos; i += 256) {
    unsigned int r = recs[i];
    int eid = (int)(r >> BSHIFT);
    int tl  = (int)(r & (BNODES - 1));
    uint4 m = mp[(size_t)eid];
    float f0 = asf(m.x << 16), f1 = asf(m.x & 0xffff0000u);
    float f2 = asf(m.y << 16), f3 = asf(m.y & 0xffff0000u);
    float f4 = asf(m.z << 16), f5 = asf(m.z & 0xffff0000u);
    float f6 = asf(m.w << 16), f7 = asf(m.w & 0xffff0000u);
    atomicAdd((unsigned long long*)&acc[tl][0], (unsigned long long)(long long)(f0 * FIXSCALE));
    atomicAdd((unsigned long long*)&acc[tl][1], (unsigned long long)(long long)(f1 * FIXSCALE));
    atomicAdd((unsigned long long*)&acc[tl][2], (unsigned long long)(long long)(f2 * FIXSCALE));
    atomicAdd((unsigned long long*)&acc[tl][3], (unsigned long long)(long long)(f3 * FIXSCALE));
    atomicAdd((unsigned long long*)&acc[tl][4], (unsigned long long)(long long)(f4 * FIXSCALE));
    atomicAdd((unsigned long long*)&acc[tl][5], (unsigned long long)(long long)(f5 * FIXSCALE));
    atomicAdd((unsigned long long*)&acc[tl][6], (unsigned long long)(long long)(f6 * FIXSCALE));
    atomicAdd((unsigned long long*)&acc[tl][7], (unsigned long long)(long long)(f7 * FIXSCALE));
    atomicAdd(&cnt[tl], 1);
  }
  __syncthreads();

  int n = b * BNODES + tid;
  if (tid < BNODES && n < N) {
    float inv = 1.f / fmaxf((float)cnt[tid], 1.f);
    float r[LAT];
#pragma unroll
    for (int o = 0; o < LAT; o++)
      r[o] = fmaf((float)((double)acc[tid][o] * FIXINV), inv, cb[o]);

    float x[EMB];
    const float4* np4 = reinterpret_cast<const float4*>(emb) + (size_t)n * (EMB / 4);
#pragma unroll
    for (int i = 0; i < EMB / 4; i++) {
      float4 v = np4[i];
      x[4 * i + 0] = v.x; x[4 * i + 1] = v.y; x[4 * i + 2] = v.z; x[4 * i + 3] = v.w;
    }
#pragma unroll
    for (int i = 0; i < EMB; i++)
#pragma unroll
      for (int o = 0; o < LAT; o++) r[o] = fmaf(x[i], rw[i * LAT + o], r[o]);

    float4* lp = reinterpret_cast<float4*>(latent) + (size_t)n * 2;
    lp[0] = make_float4(r[0], r[1], r[2], r[3]);
    lp[1] = make_float4(r[4], r[5], r[6], r[7]);
  }
}

// ---------------------------------------------------------------------------
// Decoder: fragment-major dW1f (K-pad baked in), conflict-free LDS reads.
// ---------------------------------------------------------------------------
__global__ __launch_bounds__(256, 4) void dec_mfma_kernel(
    const int* __restrict__ ei, const float* __restrict__ lat,
    const short* __restrict__ dW1f, const float* __restrict__ db1,
    const short* __restrict__ dW2p, const float* __restrict__ db2,
    float* __restrict__ out, int E) {
  __shared__ short lds_w1[4096];   // fragment-major, lh>=2 zero
  __shared__ short lds_w2[2048];   // dec GEMM2' fragments
  __shared__ float lds_b1[64];
  __shared__ float lds_b2[32];

  const int tid = threadIdx.x;
  const int w = tid >> 6, l = tid & 63;
  const int lh = l >> 4, ll = l & 15;
  const int ebase = blockIdx.x * 256 + w * 64;

  {
#pragma unroll
    for (int i = 0; i < 2; i++)
      reinterpret_cast<int4*>(lds_w1)[i * 256 + tid] =
          reinterpret_cast<const int4*>(dW1f)[i * 256 + tid];
    reinterpret_cast<int4*>(lds_w2)[tid] = reinterpret_cast<const int4*>(dW2p)[tid];
    if (tid < 64) lds_b1[tid] = db1[tid];
    if (tid < 32) lds_b2[tid] = db2[tid];
  }
  __syncthreads();

  const f32x4 z = {0.f, 0.f, 0.f, 0.f};

#pragma unroll
  for (int mt = 0; mt < 4; mt++) {
    // latent halves: lh=0 -> src, lh=1 -> tgt, lh>=2 zero pad (k 16..31)
    s16x8 af = (s16x8){0, 0, 0, 0, 0, 0, 0, 0};
    if (lh < 2) {
      int rowA = min(ebase + mt * 16 + ll, E - 1);
      int node = ei[(lh == 0 ? 0 : E) + rowA];
      const float4* lp = reinterpret_cast<const float4*>(lat + (size_t)node * LAT);
      float4 p0 = lp[0], p1 = lp[1];
      af[0]=f2b(p0.x); af[1]=f2b(p0.y); af[2]=f2b(p0.z); af[3]=f2b(p0.w);
      af[4]=f2b(p1.x); af[5]=f2b(p1.y); af[6]=f2b(p1.z); af[7]=f2b(p1.w);
    }

    f32x4 c1t[4];
#pragma unroll
    for (int ct = 0; ct < 4; ct++) {
      s16x8 b1f = *reinterpret_cast<const s16x8*>(lds_w1 + ((ct * 4 + lh) * 16 + ll) * 8);
      c1t[ct] = __builtin_amdgcn_mfma_f32_16x16x32_bf16(b1f, af, z, 0, 0, 0);
    }

    short hb[4][4];
#pragma unroll
    for (int ct = 0; ct < 4; ct++) {
      float4 bv = *reinterpret_cast<const float4*>(lds_b1 + ct * 16 + lh * 4);  // broadcast
      hb[ct][0] = f2b(fmaxf(c1t[ct][0] + bv.x, 0.f));
      hb[ct][1] = f2b(fmaxf(c1t[ct][1] + bv.y, 0.f));
      hb[ct][2] = f2b(fmaxf(c1t[ct][2] + bv.z, 0.f));
      hb[ct][3] = f2b(fmaxf(c1t[ct][3] + bv.w, 0.f));
    }
    s16x8 a2f0, a2f1;
#pragma unroll
    for (int j = 0; j < 8; j++) a2f0[j] = hb[(j >> 2)][j & 3];
#pragma unroll
    for (int j = 0; j < 8; j++) a2f1[j] = hb[2 + (j >> 2)][j & 3];

    int e = ebase + mt * 16 + ll;
#pragma unroll
    for (int ct2 = 0; ct2 < 2; ct2++) {
      s16x8 f0 = *reinterpret_cast<const s16x8*>(lds_w2 + ((ct2 * 2 + 0) * 4 + lh) * 128 + ll * 8);
      s16x8 f1 = *reinterpret_cast<const s16x8*>(lds_w2 + ((ct2 * 2 + 1) * 4 + lh) * 128 + ll * 8);
      f32x4 c2 = __builtin_amdgcn_mfma_f32_16x16x32_bf16(f0, a2f0, z, 0, 0, 0);
      c2 = __builtin_amdgcn_mfma_f32_16x16x32_bf16(f1, a2f1, c2, 0, 0, 0);
      float4 bv = *reinterpret_cast<const float4*>(lds_b2 + ct2 * 16 + lh * 4);  // broadcast
      if (e < E)
        *reinterpret_cast<float4*>(out + (size_t)e * EDIM + ct2 * 16 + lh * 4) =
            make_float4(c2[0] + bv.x, c2[1] + bv.y, c2[2] + bv.z, c2[3] + bv.w);
    }
  }
}

// ---------------------------------------------------------------------------
extern "C" void kernel_launch(void* const* d_in, const int* in_sizes, int n_in,
                              void* d_out, int out_size, void* d_ws, size_t ws_size,
                              hipStream_t stream) {
  const int*   ei    = (const int*)  d_in[0];
  const float* attr  = (const float*)d_in[1];
  const float* emb   = (const float*)d_in[2];
  const float* ewW1  = (const float*)d_in[3];
  const float* ewb1  = (const float*)d_in[4];
  const float* ewW2  = (const float*)d_in[5];
  const float* ewb2  = (const float*)d_in[6];
  const float* rootW = (const float*)d_in[7];
  const float* convb = (const float*)d_in[8];
  const float* dW1   = (const float*)d_in[9];
  const float* db1   = (const float*)d_in[10];
  const float* dW2   = (const float*)d_in[11];
  const float* db2   = (const float*)d_in[12];
  float* out = (float*)d_out;

  const int E     = in_sizes[0] / 2;
  const int N     = in_sizes[2] / EMB;
  const int nbuck = (N + BNODES - 1) >> BSHIFT;

  // workspace layout (weights first: 16B-aligned fragment loads)
  short* W1f  = (short*)d_ws;                   // 2048 shorts
  short* W2p  = W1f + 2048;                     // 8192
  short* dW1f = W2p + 8192;                     // 4096 (K-pad baked)
  short* dW2p = dW1f + 4096;                    // 2048
  unsigned int* b2pp = (unsigned int*)(dW2p + 2048);  // 64 u32
  short* ms   = (short*)(b2pp + 64);            // E*8 bf16 (16B/message)
  float* lat  = (float*)(ms + (size_t)E * LAT); // N*8
  unsigned int* recs = (unsigned int*)(lat + (size_t)N * LAT);  // E
  int* bins   = (int*)(recs + E);               // nbuck
  int* bases  = bins + nbuck;                   // nbuck+1
  int* cursor = bases + nbuck + 1;              // nbuck

  const int blocks_e = (E + 255) / 256;
  const int blocks_p = (E + PCHUNK - 1) / PCHUNK;

  hipMemsetAsync(bins, 0, (size_t)nbuck * sizeof(int), stream);
  prep_kernel<<<32, 256, 0, stream>>>(ewW1, ewW2, ewb2, dW1, dW2,
                                      W1f, W2p, b2pp, dW1f, dW2p);
  bhist_kernel<<<256, 256, 0, stream>>>(ei, bins, E, nbuck);
  bscan_kernel<<<1, 1024, 0, stream>>>(bins, bases, cursor, nbuck);
  part_kernel<<<blocks_p, 256, 0, stream>>>(ei, cursor, recs, E, nbuck);
  enc_mfma_kernel<<<blocks_e, 256, 0, stream>>>(ei, attr, emb, W1f, ewb1, W2p, b2pp,
                                                ms, E);
  agg_kernel<<<nbuck, 256, 0, stream>>>(emb, ms, recs, bases, rootW, convb, lat, N);
  dec_mfma_kernel<<<blocks_e, 256, 0, stream>>>(ei, lat, dW1f, db1, dW2p, db2, out, E);
}

// Round 17
// 212.778 us; speedup vs baseline: 3.2064x; 1.0164x over previous
//
#include <hip/hip_runtime.h>
#include <hip/hip_bf16.h>

typedef __attribute__((ext_vector_type(8))) short  s16x8;
typedef __attribute__((ext_vector_type(4))) float  f32x4;

constexpr int EMB  = 16;
constexpr int LAT  = 8;
constexpr int EDIM = 32;
constexpr int HID  = 64;

constexpr int BSHIFT = 7;                 // 128 nodes per bucket
constexpr int BNODES = 1 << BSHIFT;
constexpr int PCHUNK = 8192;              // edges per partition block

__device__ __forceinline__ short f2b(float f) {
  __hip_bfloat16 h = __float2bfloat16(f);
  return __builtin_bit_cast(short, h);
}
__device__ __forceinline__ float asf(unsigned int u) { return __builtin_bit_cast(float, u); }
__device__ __forceinline__ unsigned int pk2(float lo, float hi) {
  return ((unsigned int)(unsigned short)f2b(hi) << 16) |
         (unsigned int)(unsigned short)f2b(lo);
}

// fixed-point scale 2^40 (deterministic i64 aggregation)
#define FIXSCALE 1.0995116277760e12f
#define FIXINV   9.094947017729282e-13

// ---------------------------------------------------------------------------
// Prep (all bf16) + zero the bucket-histogram bins (saves a memset dispatch):
//  W1f  fragment-major: [(ct*4+lh)*16+ll][8j] = W1[(lh*8+j)*64 + ct*16+ll]
//  W2p  GEMM2' fragments, k-map g(kt,lh,j)=(kt*2+(j>>2))*16+lh*4+(j&3)
//       + column perm pi: i = 2*ct2+((r>>1)&1), o = 2*(r>>2)+(r&1)
//  b2pp packed epilogue bias
//  dW1f fragment-major with K-pad zeros baked in (4096 entries; lh>=2 zero)
//  dW2p dec GEMM2' fragments
// ---------------------------------------------------------------------------
__global__ void prep_kernel(const float* __restrict__ W1, const float* __restrict__ W2,
                            const float* __restrict__ b2,
                            const float* __restrict__ dW1, const float* __restrict__ dW2,
                            short* __restrict__ W1f, short* __restrict__ W2p,
                            unsigned int* __restrict__ b2pp,
                            short* __restrict__ dW1f, short* __restrict__ dW2p,
                            int* __restrict__ bins, int nbuck) {
  int t = blockIdx.x * blockDim.x + threadIdx.x;
  if (t < nbuck) bins[t] = 0;
  if (t < 2048) {
    int j = t & 7, ll = (t >> 3) & 15, lh = (t >> 7) & 3, ct = t >> 9;
    W1f[t] = f2b(W1[(lh * 8 + j) * 64 + ct * 16 + ll]);
  }
  if (t < 8192) {
    int ct2 = t >> 10, kt = (t >> 9) & 1, lh = (t >> 7) & 3, r = (t >> 3) & 15, j = t & 7;
    int k = (kt * 2 + (j >> 2)) * 16 + lh * 4 + (j & 3);
    int i = 2 * ct2 + ((r >> 1) & 1);
    int o = 2 * (r >> 2) + (r & 1);
    W2p[t] = f2b(W2[k * 128 + i * 8 + o]);
  }
  if (t < 64) {
    int lh = t >> 4, slot = t & 15;
    int ct2 = slot >> 1, ih = slot & 1;
    int i = 2 * ct2 + ih;
    unsigned int lo = (unsigned short)f2b(b2[i * 8 + 2 * lh]);
    unsigned int hi = (unsigned short)f2b(b2[i * 8 + 2 * lh + 1]);
    b2pp[t] = (hi << 16) | lo;
  }
  if (t < 4096) {
    int j = t & 7, ll = (t >> 3) & 15, lh = (t >> 7) & 3, ct = t >> 9;  // ct<4
    dW1f[t] = (lh < 2) ? f2b(dW1[(lh * 8 + j) * 64 + ct * 16 + ll]) : (short)0;
  }
  if (t < 2048) {
    int ct2 = t >> 10, kt = (t >> 9) & 1, lh = (t >> 7) & 3, r = (t >> 3) & 15, j = t & 7;
    int k = (kt * 2 + (j >> 2)) * 16 + lh * 4 + (j & 3);
    dW2p[t] = f2b(dW2[k * 32 + ct2 * 16 + r]);
  }
}

// ---------------------------------------------------------------------------
// Bucket histogram + single-block exclusive scan + partition
// ---------------------------------------------------------------------------
__global__ __launch_bounds__(256) void bhist_kernel(const int* __restrict__ ei,
                                                    int* __restrict__ bins,
                                                    int E, int nbuck) {
  __shared__ int h[1024];
  for (int i = threadIdx.x; i < nbuck; i += 256) h[i] = 0;
  __syncthreads();
  for (int e = blockIdx.x * blockDim.x + threadIdx.x; e < E; e += gridDim.x * blockDim.x)
    atomicAdd(&h[ei[E + e] >> BSHIFT], 1);
  __syncthreads();
  for (int i = threadIdx.x; i < nbuck; i += 256)
    if (h[i]) atomicAdd(&bins[i], h[i]);
}

__global__ __launch_bounds__(1024) void bscan_kernel(const int* __restrict__ bins,
                                                     int* __restrict__ bases,
                                                     int* __restrict__ cursor, int nbuck) {
  __shared__ int sh[1024];
  int tid = threadIdx.x;
  int v = (tid < nbuck) ? bins[tid] : 0;
  sh[tid] = v;
  __syncthreads();
  for (int off = 1; off < 1024; off <<= 1) {
    int t = (tid >= off) ? sh[tid - off] : 0;
    __syncthreads();
    sh[tid] += t;
    __syncthreads();
  }
  int ex = sh[tid] - v;
  if (tid < nbuck) { bases[tid] = ex; cursor[tid] = ex; }
  if (tid == 0) bases[nbuck] = sh[1023];
}

__global__ __launch_bounds__(256) void part_kernel(const int* __restrict__ ei,
                                                   int* __restrict__ cursor,
                                                   unsigned int* __restrict__ recs,
                                                   int E, int nbuck) {
  __shared__ int h[1024];
  __shared__ int gcl[1024];
  __shared__ int lr[1024];
  const int tid  = threadIdx.x;
  const int base = blockIdx.x * PCHUNK;

  for (int i = tid; i < nbuck; i += 256) { h[i] = 0; lr[i] = 0; }
  __syncthreads();
  for (int i = tid; i < PCHUNK; i += 256) {
    int e = base + i;
    if (e < E) atomicAdd(&h[ei[E + e] >> BSHIFT], 1);
  }
  __syncthreads();
  for (int i = tid; i < nbuck; i += 256)
    gcl[i] = h[i] ? atomicAdd(&cursor[i], h[i]) : 0;
  __syncthreads();
  for (int i = tid; i < PCHUNK; i += 256) {
    int e = base + i;
    if (e >= E) continue;
    int tgt = ei[E + e];
    int b = tgt >> BSHIFT;
    int p = gcl[b] + atomicAdd(&lr[b], 1);
    recs[p] = ((unsigned int)e << BSHIFT) | (unsigned int)(tgt & (BNODES - 1));
  }
}

// ---------------------------------------------------------------------------
// Encoder: weights LDS-staged (fragment-major W1f: conflict-free), attr
// prefetched, EDGE-ORDER coalesced bf16 message store (no atomics).
// (256,4): verified spill-free (rounds 8/16).
// ---------------------------------------------------------------------------
__global__ __launch_bounds__(256, 4) void enc_mfma_kernel(
    const int* __restrict__ ei, const float* __restrict__ attr,
    const float* __restrict__ emb,
    const short* __restrict__ W1f, const float* __restrict__ b1,
    const short* __restrict__ W2p, const unsigned int* __restrict__ b2pp,
    short* __restrict__ ms, int E) {
  __shared__ short lds_w1[2048];          // fragment-major
  __shared__ short lds_w2[8192];          // GEMM2' fragments
  __shared__ float lds_b1[64];
  __shared__ unsigned int lds_b2[64];

  const int tid = threadIdx.x;
  const int w = tid >> 6, l = tid & 63;
  const int lh = l >> 4, ll = l & 15;
  const int ebase = blockIdx.x * 256 + w * 64;

  // cooperative weight staging (coalesced 16B per thread)
  {
    reinterpret_cast<int4*>(lds_w1)[tid] = reinterpret_cast<const int4*>(W1f)[tid];
#pragma unroll
    for (int i = 0; i < 4; i++)
      reinterpret_cast<int4*>(lds_w2)[i * 256 + tid] =
          reinterpret_cast<const int4*>(W2p)[i * 256 + tid];
    if (tid < 64) lds_b1[tid] = b1[tid];
    if (tid < 64) lds_b2[tid] = b2pp[tid];
  }

  // phase 0: gather src embedding, pack to bf16 pairs
  unsigned int xqp[8];
  {
    int ec = min(ebase + l, E - 1);
    int src = ei[ec];
    const float4* er = reinterpret_cast<const float4*>(emb) + (size_t)src * 4;
    float4 v0 = er[0], v1 = er[1], v2 = er[2], v3 = er[3];
    xqp[0] = pk2(v0.x, v0.y); xqp[1] = pk2(v0.z, v0.w);
    xqp[2] = pk2(v1.x, v1.y); xqp[3] = pk2(v1.z, v1.w);
    xqp[4] = pk2(v2.x, v2.y); xqp[5] = pk2(v2.z, v2.w);
    xqp[6] = pk2(v3.x, v3.y); xqp[7] = pk2(v3.z, v3.w);
  }

  // prefetch attr rows for all 4 tiles, convert to bf16 fragments (16 regs)
  s16x8 afs[4];
#pragma unroll
  for (int mt = 0; mt < 4; mt++) {
    int rowA = min(ebase + mt * 16 + ll, E - 1);
    const float4* ap = reinterpret_cast<const float4*>(attr + (size_t)rowA * EDIM + lh * 8);
    float4 a0 = ap[0], a1 = ap[1];
    afs[mt][0]=f2b(a0.x); afs[mt][1]=f2b(a0.y); afs[mt][2]=f2b(a0.z); afs[mt][3]=f2b(a0.w);
    afs[mt][4]=f2b(a1.x); afs[mt][5]=f2b(a1.y); afs[mt][6]=f2b(a1.z); afs[mt][7]=f2b(a1.w);
  }

  __syncthreads();

  const f32x4 z = {0.f, 0.f, 0.f, 0.f};

#pragma unroll
  for (int mt = 0; mt < 4; mt++) {
    // GEMM1' -> H^T fragments (fragment-major: conflict-free)
    f32x4 c1t[4];
#pragma unroll
    for (int ct = 0; ct < 4; ct++) {
      s16x8 b1f = *reinterpret_cast<const s16x8*>(lds_w1 + ((ct * 4 + lh) * 16 + ll) * 8);
      c1t[ct] = __builtin_amdgcn_mfma_f32_16x16x32_bf16(b1f, afs[mt], z, 0, 0, 0);
    }

    short hb[4][4];
#pragma unroll
    for (int ct = 0; ct < 4; ct++) {
      float4 bv = *reinterpret_cast<const float4*>(lds_b1 + ct * 16 + lh * 4);  // broadcast
      hb[ct][0] = f2b(fmaxf(c1t[ct][0] + bv.x, 0.f));
      hb[ct][1] = f2b(fmaxf(c1t[ct][1] + bv.y, 0.f));
      hb[ct][2] = f2b(fmaxf(c1t[ct][2] + bv.z, 0.f));
      hb[ct][3] = f2b(fmaxf(c1t[ct][3] + bv.w, 0.f));
    }
    s16x8 a2f0, a2f1;
#pragma unroll
    for (int j = 0; j < 8; j++) a2f0[j] = hb[(j >> 2)][j & 3];
#pragma unroll
    for (int j = 0; j < 8; j++) a2f1[j] = hb[2 + (j >> 2)][j & 3];

    // fetch xe pairs of edge mt*16+ll (from the owning lane)
    const int srcl = mt * 16 + ll;
    unsigned int xs[8];
#pragma unroll
    for (int c = 0; c < 8; c++)
      xs[c] = (unsigned int)__shfl((int)xqp[c], srcl, 64);

    // GEMM2' + lane-local epilogue with bias (weights + bias from LDS)
    float q0 = 0.f, q1 = 0.f;
#pragma unroll
    for (int ct2 = 0; ct2 < 8; ct2++) {
      s16x8 f0 = *reinterpret_cast<const s16x8*>(lds_w2 + ((ct2 * 2 + 0) * 4 + lh) * 128 + ll * 8);
      s16x8 f1 = *reinterpret_cast<const s16x8*>(lds_w2 + ((ct2 * 2 + 1) * 4 + lh) * 128 + ll * 8);
      f32x4 c2 = __builtin_amdgcn_mfma_f32_16x16x32_bf16(f0, a2f0, z, 0, 0, 0);
      c2 = __builtin_amdgcn_mfma_f32_16x16x32_bf16(f1, a2f1, c2, 0, 0, 0);
      uint2 pp = *reinterpret_cast<const uint2*>(lds_b2 + lh * 16 + 2 * ct2);  // broadcast
      float b00 = asf(pp.x << 16), b01 = asf(pp.x & 0xffff0000u);
      float b10 = asf(pp.y << 16), b11 = asf(pp.y & 0xffff0000u);
      float xv0 = asf(xs[ct2] << 16);          // xe[2*ct2]
      float xv1 = asf(xs[ct2] & 0xffff0000u);  // xe[2*ct2+1]
      q0 = fmaf(xv0, c2[0] + b00, q0);
      q1 = fmaf(xv0, c2[1] + b01, q1);
      q0 = fmaf(xv1, c2[2] + b10, q0);
      q1 = fmaf(xv1, c2[3] + b11, q1);
    }
    // coalesced bf16 store in EDGE order
    int e = ebase + mt * 16 + ll;
    if (e < E)
      *reinterpret_cast<unsigned int*>(ms + (size_t)e * LAT + 2 * lh) = pk2(q0, q1);
  }
}

// ---------------------------------------------------------------------------
// Aggregate: one block per bucket. Contiguous record read, random ms gather
// (L3-resident), deterministic i64 fixed-point LDS accumulation (padded rows),
// then mean + conv_b + emb@rootW -> latent.
// ---------------------------------------------------------------------------
__global__ __launch_bounds__(256) void agg_kernel(
    const float* __restrict__ emb, const short* __restrict__ ms,
    const unsigned int* __restrict__ recs, const int* __restrict__ bases,
    const float* __restrict__ rootW, const float* __restrict__ convb,
    float* __restrict__ latent, int N) {
  __shared__ long long acc[BNODES][LAT + 1];   // 72B rows: bank de-alias
  __shared__ int cnt[BNODES];
  __shared__ float rw[EMB * LAT];
  __shared__ float cb[LAT];

  const int tid = threadIdx.x;
  const int b = blockIdx.x;

  long long* af = &acc[0][0];
  for (int i = tid; i < BNODES * (LAT + 1); i += 256) af[i] = 0;
  if (tid < BNODES) cnt[tid] = 0;
  if (tid < EMB * LAT) rw[tid] = rootW[tid];
  if (tid < LAT) cb[tid] = convb[tid];
  __syncthreads();

  const int s = bases[b], epos = bases[b + 1];
  const uint4* mp = reinterpret_cast<const uint4*>(ms);
  for (int i = s + tid; i < epos; i += 256) {
    unsigned int r = recs[i];
    int eid = (int)(r >> BSHIFT);
    int tl  = (int)(r & (BNODES - 1));
    uint4 m = mp[(size_t)eid];
    float f0 = asf(m.x << 16), f1 = asf(m.x & 0xffff0000u);
    float f2 = asf(m.y << 16), f3 = asf(m.y & 0xffff0000u);
    float f4 = asf(m.z << 16), f5 = asf(m.z & 0xffff0000u);
    float f6 = asf(m.w << 16), f7 = asf(m.w & 0xffff0000u);
    atomicAdd((unsigned long long*)&acc[tl][0], (unsigned long long)(long long)(f0 * FIXSCALE));
    atomicAdd((unsigned long long*)&acc[tl][1], (unsigned long long)(long long)(f1 * FIXSCALE));
    atomicAdd((unsigned long long*)&acc[tl][2], (unsigned long long)(long long)(f2 * FIXSCALE));
    atomicAdd((unsigned long long*)&acc[tl][3], (unsigned long long)(long long)(f3 * FIXSCALE));
    atomicAdd((unsigned long long*)&acc[tl][4], (unsigned long long)(long long)(f4 * FIXSCALE));
    atomicAdd((unsigned long long*)&acc[tl][5], (unsigned long long)(long long)(f5 * FIXSCALE));
    atomicAdd((unsigned long long*)&acc[tl][6], (unsigned long long)(long long)(f6 * FIXSCALE));
    atomicAdd((unsigned long long*)&acc[tl][7], (unsigned long long)(long long)(f7 * FIXSCALE));
    atomicAdd(&cnt[tl], 1);
  }
  __syncthreads();

  int n = b * BNODES + tid;
  if (tid < BNODES && n < N) {
    float inv = 1.f / fmaxf((float)cnt[tid], 1.f);
    float r[LAT];
#pragma unroll
    for (int o = 0; o < LAT; o++)
      r[o] = fmaf((float)((double)acc[tid][o] * FIXINV), inv, cb[o]);

    float x[EMB];
    const float4* np4 = reinterpret_cast<const float4*>(emb) + (size_t)n * (EMB / 4);
#pragma unroll
    for (int i = 0; i < EMB / 4; i++) {
      float4 v = np4[i];
      x[4 * i + 0] = v.x; x[4 * i + 1] = v.y; x[4 * i + 2] = v.z; x[4 * i + 3] = v.w;
    }
#pragma unroll
    for (int i = 0; i < EMB; i++)
#pragma unroll
      for (int o = 0; o < LAT; o++) r[o] = fmaf(x[i], rw[i * LAT + o], r[o]);

    float4* lp = reinterpret_cast<float4*>(latent) + (size_t)n * 2;
    lp[0] = make_float4(r[0], r[1], r[2], r[3]);
    lp[1] = make_float4(r[4], r[5], r[6], r[7]);
  }
}

// ---------------------------------------------------------------------------
// Decoder: fragment-major dW1f (K-pad baked in), conflict-free LDS reads.
// (256,5) occupancy probe: demand ~60 VGPR < 5-wave cap (~96); dec has never
// spilled in this session. Decision rule: FETCH/WRITE amplification => revert.
// ---------------------------------------------------------------------------
__global__ __launch_bounds__(256, 5) void dec_mfma_kernel(
    const int* __restrict__ ei, const float* __restrict__ lat,
    const short* __restrict__ dW1f, const float* __restrict__ db1,
    const short* __restrict__ dW2p, const float* __restrict__ db2,
    float* __restrict__ out, int E) {
  __shared__ short lds_w1[4096];   // fragment-major, lh>=2 zero
  __shared__ short lds_w2[2048];   // dec GEMM2' fragments
  __shared__ float lds_b1[64];
  __shared__ float lds_b2[32];

  const int tid = threadIdx.x;
  const int w = tid >> 6, l = tid & 63;
  const int lh = l >> 4, ll = l & 15;
  const int ebase = blockIdx.x * 256 + w * 64;

  {
#pragma unroll
    for (int i = 0; i < 2; i++)
      reinterpret_cast<int4*>(lds_w1)[i * 256 + tid] =
          reinterpret_cast<const int4*>(dW1f)[i * 256 + tid];
    reinterpret_cast<int4*>(lds_w2)[tid] = reinterpret_cast<const int4*>(dW2p)[tid];
    if (tid < 64) lds_b1[tid] = db1[tid];
    if (tid < 32) lds_b2[tid] = db2[tid];
  }
  __syncthreads();

  const f32x4 z = {0.f, 0.f, 0.f, 0.f};

#pragma unroll
  for (int mt = 0; mt < 4; mt++) {
    // latent halves: lh=0 -> src, lh=1 -> tgt, lh>=2 zero pad (k 16..31)
    s16x8 af = (s16x8){0, 0, 0, 0, 0, 0, 0, 0};
    if (lh < 2) {
      int rowA = min(ebase + mt * 16 + ll, E - 1);
      int node = ei[(lh == 0 ? 0 : E) + rowA];
      const float4* lp = reinterpret_cast<const float4*>(lat + (size_t)node * LAT);
      float4 p0 = lp[0], p1 = lp[1];
      af[0]=f2b(p0.x); af[1]=f2b(p0.y); af[2]=f2b(p0.z); af[3]=f2b(p0.w);
      af[4]=f2b(p1.x); af[5]=f2b(p1.y); af[6]=f2b(p1.z); af[7]=f2b(p1.w);
    }

    f32x4 c1t[4];
#pragma unroll
    for (int ct = 0; ct < 4; ct++) {
      s16x8 b1f = *reinterpret_cast<const s16x8*>(lds_w1 + ((ct * 4 + lh) * 16 + ll) * 8);
      c1t[ct] = __builtin_amdgcn_mfma_f32_16x16x32_bf16(b1f, af, z, 0, 0, 0);
    }

    short hb[4][4];
#pragma unroll
    for (int ct = 0; ct < 4; ct++) {
      float4 bv = *reinterpret_cast<const float4*>(lds_b1 + ct * 16 + lh * 4);  // broadcast
      hb[ct][0] = f2b(fmaxf(c1t[ct][0] + bv.x, 0.f));
      hb[ct][1] = f2b(fmaxf(c1t[ct][1] + bv.y, 0.f));
      hb[ct][2] = f2b(fmaxf(c1t[ct][2] + bv.z, 0.f));
      hb[ct][3] = f2b(fmaxf(c1t[ct][3] + bv.w, 0.f));
    }
    s16x8 a2f0, a2f1;
#pragma unroll
    for (int j = 0; j < 8; j++) a2f0[j] = hb[(j >> 2)][j & 3];
#pragma unroll
    for (int j = 0; j < 8; j++) a2f1[j] = hb[2 + (j >> 2)][j & 3];

    int e = ebase + mt * 16 + ll;
#pragma unroll
    for (int ct2 = 0; ct2 < 2; ct2++) {
      s16x8 f0 = *reinterpret_cast<const s16x8*>(lds_w2 + ((ct2 * 2 + 0) * 4 + lh) * 128 + ll * 8);
      s16x8 f1 = *reinterpret_cast<const s16x8*>(lds_w2 + ((ct2 * 2 + 1) * 4 + lh) * 128 + ll * 8);
      f32x4 c2 = __builtin_amdgcn_mfma_f32_16x16x32_bf16(f0, a2f0, z, 0, 0, 0);
      c2 = __builtin_amdgcn_mfma_f32_16x16x32_bf16(f1, a2f1, c2, 0, 0, 0);
      float4 bv = *reinterpret_cast<const float4*>(lds_b2 + ct2 * 16 + lh * 4);  // broadcast
      if (e < E)
        *reinterpret_cast<float4*>(out + (size_t)e * EDIM + ct2 * 16 + lh * 4) =
            make_float4(c2[0] + bv.x, c2[1] + bv.y, c2[2] + bv.z, c2[3] + bv.w);
    }
  }
}

// ---------------------------------------------------------------------------
extern "C" void kernel_launch(void* const* d_in, const int* in_sizes, int n_in,
                              void* d_out, int out_size, void* d_ws, size_t ws_size,
                              hipStream_t stream) {
  const int*   ei    = (const int*)  d_in[0];
  const float* attr  = (const float*)d_in[1];
  const float* emb   = (const float*)d_in[2];
  const float* ewW1  = (const float*)d_in[3];
  const float* ewb1  = (const float*)d_in[4];
  const float* ewW2  = (const float*)d_in[5];
  const float* ewb2  = (const float*)d_in[6];
  const float* rootW = (const float*)d_in[7];
  const float* convb = (const float*)d_in[8];
  const float* dW1   = (const float*)d_in[9];
  const float* db1   = (const float*)d_in[10];
  const float* dW2   = (const float*)d_in[11];
  const float* db2   = (const float*)d_in[12];
  float* out = (float*)d_out;

  const int E     = in_sizes[0] / 2;
  const int N     = in_sizes[2] / EMB;
  const int nbuck = (N + BNODES - 1) >> BSHIFT;

  // workspace layout (weights first: 16B-aligned fragment loads)
  short* W1f  = (short*)d_ws;                   // 2048 shorts
  short* W2p  = W1f + 2048;                     // 8192
  short* dW1f = W2p + 8192;                     // 4096 (K-pad baked)
  short* dW2p = dW1f + 4096;                    // 2048
  unsigned int* b2pp = (unsigned int*)(dW2p + 2048);  // 64 u32
  short* ms   = (short*)(b2pp + 64);            // E*8 bf16 (16B/message)
  float* lat  = (float*)(ms + (size_t)E * LAT); // N*8
  unsigned int* recs = (unsigned int*)(lat + (size_t)N * LAT);  // E
  int* bins   = (int*)(recs + E);               // nbuck
  int* bases  = bins + nbuck;                   // nbuck+1
  int* cursor = bases + nbuck + 1;              // nbuck

  const int blocks_e = (E + 255) / 256;
  const int blocks_p = (E + PCHUNK - 1) / PCHUNK;

  prep_kernel<<<32, 256, 0, stream>>>(ewW1, ewW2, ewb2, dW1, dW2,
                                      W1f, W2p, b2pp, dW1f, dW2p, bins, nbuck);
  bhist_kernel<<<256, 256, 0, stream>>>(ei, bins, E, nbuck);
  bscan_kernel<<<1, 1024, 0, stream>>>(bins, bases, cursor, nbuck);
  part_kernel<<<blocks_p, 256, 0, stream>>>(ei, cursor, recs, E, nbuck);
  enc_mfma_kernel<<<blocks_e, 256, 0, stream>>>(ei, attr, emb, W1f, ewb1, W2p, b2pp,
                                                ms, E);
  agg_kernel<<<nbuck, 256, 0, stream>>>(emb, ms, recs, bases, rootW, convb, lat, N);
  dec_mfma_kernel<<<blocks_e, 256, 0, stream>>>(ei, lat, dW1f, db1, dW2p, db2, out, E);
}